// Round 5
// baseline (77.291 us; speedup 1.0000x reference)
//
#include <hip/hip_runtime.h>

#define BDIM 1024      // 16 waves: each wave owns a 32-gaussian chunk
#define NW   16
#define RPB  64        // rays per block (one per lane)
#define NG   512       // gaussians (N)
#define GPW  (NG / NW) // 32 gaussians per wave

// ---------------------------------------------------------------------------
// Params are wave-uniform -> keep them OUT of LDS. pre_kernel packs:
//   wsA[n] = (ax, ay, bx, by)                cheap-test affine, float4
//   wsH[n] = [c, s, w0, 1/Sx, 1/Sy, sh*27]   heavy row, 32 floats = 128 B
// splat_kernel indexes both with readfirstlane-scalarized addresses so the
// compiler emits s_load via the constant cache: zero LDS / VMEM traffic in
// the gaussian loop (R4 burned ~12k cyc/CU of LDS pipe on broadcast
// ds_read_b128). SH coefficients become scalar operands of the fmas.
// LDS = 12 KB (cross-wave reduce only); 2 blocks/CU = 32 waves/CU.
// ---------------------------------------------------------------------------

__global__ void pre_kernel(const float* __restrict__ rgbsh,
                           const float* __restrict__ opacity,
                           const float* __restrict__ mu,
                           const float* __restrict__ scale,
                           const float* __restrict__ angle,
                           float4* __restrict__ wsA,
                           float*  __restrict__ wsH,   // [N][32]
                           int N)
{
    int n = blockIdx.x * blockDim.x + threadIdx.x;
    if (n >= N) return;
    const float S_MIN = 1.0f / 30.0f;
    const float S_MAX = 1.0f / 0.75f;
    float gmx = tanhf(mu[2 * n + 0]) * 1.05f;
    float gmy = tanhf(mu[2 * n + 1]) * 1.05f;
    float Sx = fminf(fmaxf(scale[2 * n + 0], 0.0f), 1.0f) * (S_MAX - S_MIN) + S_MIN;
    float Sy = fminf(fmaxf(scale[2 * n + 1], 0.0f), 1.0f) * (S_MAX - S_MIN) + S_MIN;
    float ax = 256.0f * Sx, ay = 256.0f * Sy;      // svec = pn*a + b
    wsA[n] = make_float4(ax, ay, -gmx * ax, -gmy * ay);
    float a = tanhf(angle[n]) * 3.1416f;
    float sa, ca;
    sincosf(a, &sa, &ca);
    float* hp = wsH + ((size_t)n << 5);
    hp[0] = ca;
    hp[1] = sa;
    hp[2] = 1.0f / (1.0f + expf(-opacity[n]));
    hp[3] = 1.0f / Sx;
    hp[4] = 1.0f / Sy;
    #pragma unroll
    for (int q = 0; q < 27; ++q) hp[5 + q] = rgbsh[n * 27 + q];
}

__global__ __launch_bounds__(BDIM, 8) void splat_kernel(
    const float*  __restrict__ x,      // (B,2)
    const float4* __restrict__ wsA,
    const float*  __restrict__ wsH,    // [N][32]
    float* __restrict__ out,           // (B,3)
    int B)
{
    __shared__ float acc[NW][RPB * 3];     // 12 KB, cross-wave reduce only
    const int tid  = threadIdx.x;
    const int lane = tid & 63;
    // force the wave id scalar so all param addresses are provably uniform
    const int w = __builtin_amdgcn_readfirstlane(tid >> 6);

    const int b  = blockIdx.x * RPB + lane;
    const int bb = (b < B) ? b : (B - 1);
    float2 p2 = *(const float2*)(x + 2 * bb);
    float pnx = p2.x * (1.0f / 256.0f) - 1.0f;
    float pny = p2.y * (1.0f / 256.0f) - 1.0f;

    float accR = 0.0f, accG = 0.0f, accB = 0.0f;
    const float4* __restrict__ wA = wsA + w * GPW;            // uniform base
    const float*  __restrict__ wH = wsH + ((size_t)(w * GPW) << 5);

    #pragma unroll 2
    for (int j = 0; j < GPW; ++j) {
        float4 pa = wA[j];                         // s_load_dwordx4 (uniform)
        float sx = fmaf(pnx, pa.x, pa.z);          // scaled offset
        float sy = fmaf(pny, pa.y, pa.w);
        float t  = fmaf(sx, sx, sy * sy);          // == dist^2 (R is rotation)
        bool  v  = t < 25.0f;
        if (__any(v)) {
            const float* hp = wH + (j << 5);       // uniform 128 B row
            float c   = hp[0], s = hp[1];
            float w0  = hp[2];
            float iSx = hp[3], iSy = hp[4];
            if (v) {
                float rx = fmaf(c, sx, -s * sy);
                float ry = fmaf(s, sx,  c * sy);
                float d2 = fmaf(rx, rx, ry * ry);
                float vx  = sx * iSx;              // pixel-space vec
                float vy  = sy * iSy;
                float len = sqrtf(fmaf(vx, vx, vy * vy));
                float inv = __builtin_amdgcn_rcpf(1e-10f + len);
                float rvx = fmaf(c, vx, -s * vy);
                float rvy = fmaf(s, vx,  c * vy);
                float s1 = rvx * inv, c1 = rvy * inv;
                float s2 = 2.0f * s1 * c1;
                float c2 = fmaf(c1, c1, -s1 * s1);
                float s3 = fmaf(s2, c1,  c2 * s1);
                float c3 = fmaf(c2, c1, -s2 * s1);
                float s4 = 2.0f * s2 * c2;
                float c4 = fmaf(c2, c2, -s2 * s2);
                const float* sh = hp + 5;          // scalar operands below
                float rr = sh[0], gg = sh[1], bb2 = sh[2];
                rr = fmaf(s1, sh[ 3], rr);  gg = fmaf(s1, sh[ 4], gg);  bb2 = fmaf(s1, sh[ 5], bb2);
                rr = fmaf(c1, sh[ 6], rr);  gg = fmaf(c1, sh[ 7], gg);  bb2 = fmaf(c1, sh[ 8], bb2);
                rr = fmaf(s2, sh[ 9], rr);  gg = fmaf(s2, sh[10], gg);  bb2 = fmaf(s2, sh[11], bb2);
                rr = fmaf(c2, sh[12], rr);  gg = fmaf(c2, sh[13], gg);  bb2 = fmaf(c2, sh[14], bb2);
                rr = fmaf(s3, sh[15], rr);  gg = fmaf(s3, sh[16], gg);  bb2 = fmaf(s3, sh[17], bb2);
                rr = fmaf(c3, sh[18], rr);  gg = fmaf(c3, sh[19], gg);  bb2 = fmaf(c3, sh[20], bb2);
                rr = fmaf(s4, sh[21], rr);  gg = fmaf(s4, sh[22], gg);  bb2 = fmaf(s4, sh[23], bb2);
                rr = fmaf(c4, sh[24], rr);  gg = fmaf(c4, sh[25], gg);  bb2 = fmaf(c4, sh[26], bb2);
                rr  = __builtin_amdgcn_rcpf(1.0f + __expf(-rr));
                gg  = __builtin_amdgcn_rcpf(1.0f + __expf(-gg));
                bb2 = __builtin_amdgcn_rcpf(1.0f + __expf(-bb2));
                float wt = __expf(-d2) * w0;
                accR = fmaf(wt, rr,  accR);
                accG = fmaf(wt, gg,  accG);
                accB = fmaf(wt, bb2, accB);
            }
        }
    }

    // ---- reduce partials across 16 waves (ascending chunk == ascending n) ----
    acc[w][lane * 3 + 0] = accR;     // stride-3: 2-way bank alias (free)
    acc[w][lane * 3 + 1] = accG;
    acc[w][lane * 3 + 2] = accB;
    __syncthreads();
    if (tid < RPB * 3) {
        float s = 0.0f;
        #pragma unroll
        for (int w2 = 0; w2 < NW; ++w2)
            s += acc[w2][tid];                     // consecutive: conflict-free
        const int idx = blockIdx.x * (RPB * 3) + tid;
        if (idx < 3 * B)
            out[idx] = s;
    }
}

extern "C" void kernel_launch(void* const* d_in, const int* in_sizes, int n_in,
                              void* d_out, int out_size, void* d_ws, size_t ws_size,
                              hipStream_t stream) {
    const float* x       = (const float*)d_in[0];
    const float* rgbsh   = (const float*)d_in[1];
    const float* opacity = (const float*)d_in[2];
    const float* mu      = (const float*)d_in[3];
    const float* scale   = (const float*)d_in[4];
    const float* angle   = (const float*)d_in[5];
    float* out = (float*)d_out;

    const int B = in_sizes[0] / 2;   // 32768
    const int N = in_sizes[2];       // 512

    // workspace: [wsA: N float4 (8 KB)][wsH: N*32 floats (64 KB)]
    char* ws = (char*)d_ws;
    float4* wsA = (float4*)(ws);
    float*  wsH = (float*)(ws + (size_t)N * 16);

    pre_kernel<<<(N + 255) / 256, 256, 0, stream>>>(rgbsh, opacity, mu, scale,
                                                    angle, wsA, wsH, N);
    splat_kernel<<<(B + RPB - 1) / RPB, BDIM, 0, stream>>>(x, wsA, wsH, out, B);
}

// Round 6
// 72.863 us; speedup vs baseline: 1.0608x; 1.0608x over previous
//
#include <hip/hip_runtime.h>

#define BDIM 1024      // 16 waves: each wave owns a 32-gaussian chunk
#define NW   16
#define RPB  64        // rays per block (one per lane)
#define NG   512       // gaussians (N)
#define GPW  (NG / NW) // 32 gaussians per wave
#define QCAP 256       // per-wave hit-queue capacity (flush at QCAP-64)

// ---------------------------------------------------------------------------
// Cheap test identical to R5 (scalar s_load params, wave-uniform). Heavy work
// is ballot-compacted into a per-wave LDS queue of (j<<6|lane) entries and
// drained densely: every lane services a REAL (ray,gaussian) hit instead of
// issuing the ~180-cyc heavy body with ~1/64 lanes active (R4/R5 burned ~64x
// issue on it). Dense lanes read their own 128B wsH row via vector loads and
// scatter-accumulate into the wave's private acc slice with ds_add_f32.
// LDS ~21 KB; 2 blocks/CU = 32 waves/CU.
// ---------------------------------------------------------------------------

__global__ void pre_kernel(const float* __restrict__ rgbsh,
                           const float* __restrict__ opacity,
                           const float* __restrict__ mu,
                           const float* __restrict__ scale,
                           const float* __restrict__ angle,
                           float4* __restrict__ wsA,
                           float*  __restrict__ wsH,   // [N][32]
                           int N)
{
    int n = blockIdx.x * blockDim.x + threadIdx.x;
    if (n >= N) return;
    const float S_MIN = 1.0f / 30.0f;
    const float S_MAX = 1.0f / 0.75f;
    float gmx = tanhf(mu[2 * n + 0]) * 1.05f;
    float gmy = tanhf(mu[2 * n + 1]) * 1.05f;
    float Sx = fminf(fmaxf(scale[2 * n + 0], 0.0f), 1.0f) * (S_MAX - S_MIN) + S_MIN;
    float Sy = fminf(fmaxf(scale[2 * n + 1], 0.0f), 1.0f) * (S_MAX - S_MIN) + S_MIN;
    float ax = 256.0f * Sx, ay = 256.0f * Sy;      // svec = pn*a + b
    wsA[n] = make_float4(ax, ay, -gmx * ax, -gmy * ay);
    float a = tanhf(angle[n]) * 3.1416f;
    float sa, ca;
    sincosf(a, &sa, &ca);
    float* hp = wsH + ((size_t)n << 5);
    hp[0] = ca;
    hp[1] = sa;
    hp[2] = 1.0f / (1.0f + expf(-opacity[n]));
    hp[3] = 1.0f / Sx;
    hp[4] = 1.0f / Sy;
    #pragma unroll
    for (int q = 0; q < 27; ++q) hp[5 + q] = rgbsh[n * 27 + q];
}

__global__ __launch_bounds__(BDIM, 8) void splat_kernel(
    const float*  __restrict__ x,      // (B,2)
    const float4* __restrict__ wsA,
    const float*  __restrict__ wsH,    // [N][32]
    float* __restrict__ out,           // (B,3)
    int B)
{
    __shared__ float acc[NW][RPB * 3];        // 12 KB, per-wave private slices
    __shared__ float pn[2][RPB];              // 512 B (pnx, pny per block-ray)
    __shared__ unsigned short queue[NW][QCAP];// 8 KB hit queues
    const int tid  = threadIdx.x;
    const int lane = tid & 63;
    const int w = __builtin_amdgcn_readfirstlane(tid >> 6);

    const int b  = blockIdx.x * RPB + lane;
    const int bb = (b < B) ? b : (B - 1);
    float2 p2 = *(const float2*)(x + 2 * bb);
    float pnx = p2.x * (1.0f / 256.0f) - 1.0f;
    float pny = p2.y * (1.0f / 256.0f) - 1.0f;

    if (w == 0) { pn[0][lane] = pnx; pn[1][lane] = pny; }
    #pragma unroll
    for (int c = 0; c < 3; ++c) acc[w][lane * 3 + c] = 0.0f;
    __syncthreads();   // pn visible to all waves; acc slices zeroed

    const int g0 = w * GPW;
    const float4* __restrict__ wA = wsA + g0;   // uniform base -> s_load

    int qlen = 0;

    // dense drain of this wave's hit queue (no cross-wave sync needed)
    auto flush = [&]() {
        for (int qi = lane; qi < qlen; qi += 64) {
            const int e  = queue[w][qi];
            const int l  = e & 63;
            const int g  = g0 + (e >> 6);
            const float qx = pn[0][l];
            const float qy = pn[1][l];
            const float4 pa = wsA[g];                       // per-lane vector load
            const float sx = fmaf(qx, pa.x, pa.z);
            const float sy = fmaf(qy, pa.y, pa.w);
            const float4* hp = (const float4*)(wsH + ((size_t)g << 5));
            const float4 f0 = hp[0], f1 = hp[1], f2 = hp[2], f3 = hp[3];
            const float4 f4 = hp[4], f5 = hp[5], f6 = hp[6], f7 = hp[7];
            const float c = f0.x, s = f0.y, w0 = f0.z, iSx = f0.w, iSy = f1.x;
            float rx = fmaf(c, sx, -s * sy);
            float ry = fmaf(s, sx,  c * sy);
            float d2 = fmaf(rx, rx, ry * ry);
            float vx  = sx * iSx;
            float vy  = sy * iSy;
            float len = sqrtf(fmaf(vx, vx, vy * vy));
            float inv = __builtin_amdgcn_rcpf(1e-10f + len);
            float rvx = fmaf(c, vx, -s * vy);
            float rvy = fmaf(s, vx,  c * vy);
            float s1 = rvx * inv, c1 = rvy * inv;
            float s2 = 2.0f * s1 * c1;
            float c2 = fmaf(c1, c1, -s1 * s1);
            float s3 = fmaf(s2, c1,  c2 * s1);
            float c3 = fmaf(c2, c1, -s2 * s1);
            float s4 = 2.0f * s2 * c2;
            float c4 = fmaf(c2, c2, -s2 * s2);
            float rr = f1.y, gg = f1.z, bb2 = f1.w;          // sh0..2
            rr = fmaf(s1, f2.x, rr);  gg = fmaf(s1, f2.y, gg);  bb2 = fmaf(s1, f2.z, bb2);
            rr = fmaf(c1, f2.w, rr);  gg = fmaf(c1, f3.x, gg);  bb2 = fmaf(c1, f3.y, bb2);
            rr = fmaf(s2, f3.z, rr);  gg = fmaf(s2, f3.w, gg);  bb2 = fmaf(s2, f4.x, bb2);
            rr = fmaf(c2, f4.y, rr);  gg = fmaf(c2, f4.z, gg);  bb2 = fmaf(c2, f4.w, bb2);
            rr = fmaf(s3, f5.x, rr);  gg = fmaf(s3, f5.y, gg);  bb2 = fmaf(s3, f5.z, bb2);
            rr = fmaf(c3, f5.w, rr);  gg = fmaf(c3, f6.x, gg);  bb2 = fmaf(c3, f6.y, bb2);
            rr = fmaf(s4, f6.z, rr);  gg = fmaf(s4, f6.w, gg);  bb2 = fmaf(s4, f7.x, bb2);
            rr = fmaf(c4, f7.y, rr);  gg = fmaf(c4, f7.z, gg);  bb2 = fmaf(c4, f7.w, bb2);
            rr  = __builtin_amdgcn_rcpf(1.0f + __expf(-rr));
            gg  = __builtin_amdgcn_rcpf(1.0f + __expf(-gg));
            bb2 = __builtin_amdgcn_rcpf(1.0f + __expf(-bb2));
            float wt = __expf(-d2) * w0;
            atomicAdd(&acc[w][l * 3 + 0], wt * rr);          // ds_add_f32
            atomicAdd(&acc[w][l * 3 + 1], wt * gg);
            atomicAdd(&acc[w][l * 3 + 2], wt * bb2);
        }
        qlen = 0;
    };

    #pragma unroll 2
    for (int j = 0; j < GPW; ++j) {
        float4 pa = wA[j];                         // uniform s_load_dwordx4
        float sx = fmaf(pnx, pa.x, pa.z);
        float sy = fmaf(pny, pa.y, pa.w);
        float t  = fmaf(sx, sx, sy * sy);          // == dist^2 (R is rotation)
        bool  v  = t < 25.0f;
        unsigned long long mask = __ballot(v);
        if (mask) {
            int prefix = __popcll(mask & ((1ull << lane) - 1ull));
            if (v) queue[w][qlen + prefix] = (unsigned short)((j << 6) | lane);
            qlen += __popcll(mask);
            if (qlen > QCAP - 64) flush();         // cannot overflow next iter
        }
    }
    flush();

    // ---- reduce partials across 16 waves (ascending chunk == ascending n) ----
    __syncthreads();
    if (tid < RPB * 3) {
        float s = 0.0f;
        #pragma unroll
        for (int w2 = 0; w2 < NW; ++w2)
            s += acc[w2][tid];                     // consecutive: conflict-free
        const int idx = blockIdx.x * (RPB * 3) + tid;
        if (idx < 3 * B)
            out[idx] = s;
    }
}

extern "C" void kernel_launch(void* const* d_in, const int* in_sizes, int n_in,
                              void* d_out, int out_size, void* d_ws, size_t ws_size,
                              hipStream_t stream) {
    const float* x       = (const float*)d_in[0];
    const float* rgbsh   = (const float*)d_in[1];
    const float* opacity = (const float*)d_in[2];
    const float* mu      = (const float*)d_in[3];
    const float* scale   = (const float*)d_in[4];
    const float* angle   = (const float*)d_in[5];
    float* out = (float*)d_out;

    const int B = in_sizes[0] / 2;   // 32768
    const int N = in_sizes[2];       // 512

    // workspace: [wsA: N float4 (8 KB)][wsH: N*32 floats (64 KB)]
    char* ws = (char*)d_ws;
    float4* wsA = (float4*)(ws);
    float*  wsH = (float*)(ws + (size_t)N * 16);

    pre_kernel<<<(N + 255) / 256, 256, 0, stream>>>(rgbsh, opacity, mu, scale,
                                                    angle, wsA, wsH, N);
    splat_kernel<<<(B + RPB - 1) / RPB, BDIM, 0, stream>>>(x, wsA, wsH, out, B);
}

// Round 8
// 72.098 us; speedup vs baseline: 1.0720x; 1.0106x over previous
//
#include <hip/hip_runtime.h>

#define BDIM 512       // 8 waves; wave w owns gaussians [64w, 64w+64)
#define NW   8
#define RPB  64        // rays per block
#define NG   512       // gaussians (N)
#define GPW  64        // gaussians per wave (== wavefront size)
#define QCAP 256       // per-wave hit-queue capacity (flush at QCAP-64)

// ---------------------------------------------------------------------------
// Transposed sweep: lane = GAUSSIAN, iterate over rays. The wave's 64
// gaussians' affine params live in 4 per-lane VGPRs (loaded once), and each
// ray's coords are broadcast by v_readlane with an immediate index (loop
// fully unrolled). The 16.7M-pair cheap sweep issues pure VALU -- no s_load,
// no LDS, no waitcnt. Hits are ballot-compacted into a per-wave LDS queue
// and drained densely.
//
// R7 bugfix: the drain loop now uses a WAVE-UNIFORM trip count
// (qtot = round_up(qlen,64)) so all 64 lanes are active through every
// ds_bpermute -- bpermute from an EXEC-disabled lane returns undefined data
// (that was the absmax=0.97 failure). Dead lanes clamp to queue entry 0
// (valid indices, safe loads) and skip the accumulation.
// LDS = 10 KB; grid 512 -> 2 blocks/CU = 16 waves/CU.
// ---------------------------------------------------------------------------

__global__ void pre_kernel(const float* __restrict__ rgbsh,
                           const float* __restrict__ opacity,
                           const float* __restrict__ mu,
                           const float* __restrict__ scale,
                           const float* __restrict__ angle,
                           float4* __restrict__ wsA,
                           float*  __restrict__ wsH,   // [N][32]
                           int N)
{
    int n = blockIdx.x * blockDim.x + threadIdx.x;
    if (n >= N) return;
    const float S_MIN = 1.0f / 30.0f;
    const float S_MAX = 1.0f / 0.75f;
    float gmx = tanhf(mu[2 * n + 0]) * 1.05f;
    float gmy = tanhf(mu[2 * n + 1]) * 1.05f;
    float Sx = fminf(fmaxf(scale[2 * n + 0], 0.0f), 1.0f) * (S_MAX - S_MIN) + S_MIN;
    float Sy = fminf(fmaxf(scale[2 * n + 1], 0.0f), 1.0f) * (S_MAX - S_MIN) + S_MIN;
    float ax = 256.0f * Sx, ay = 256.0f * Sy;      // svec = pn*a + b
    wsA[n] = make_float4(ax, ay, -gmx * ax, -gmy * ay);
    float a = tanhf(angle[n]) * 3.1416f;
    float sa, ca;
    sincosf(a, &sa, &ca);
    float* hp = wsH + ((size_t)n << 5);
    hp[0] = ca;
    hp[1] = sa;
    hp[2] = 1.0f / (1.0f + expf(-opacity[n]));
    hp[3] = 1.0f / Sx;
    hp[4] = 1.0f / Sy;
    #pragma unroll
    for (int q = 0; q < 27; ++q) hp[5 + q] = rgbsh[n * 27 + q];
}

__global__ __launch_bounds__(BDIM, 4) void splat_kernel(
    const float*  __restrict__ x,      // (B,2)
    const float4* __restrict__ wsA,
    const float*  __restrict__ wsH,    // [N][32]
    float* __restrict__ out,           // (B,3)
    int B)
{
    __shared__ float acc[NW][RPB * 3];         // 6 KB, per-wave private slices
    __shared__ unsigned short queue[NW][QCAP]; // 4 KB hit queues
    const int tid  = threadIdx.x;
    const int lane = tid & 63;
    const int w = __builtin_amdgcn_readfirstlane(tid >> 6);

    // per-lane GAUSSIAN params (lane = gaussian within this wave's chunk)
    const int   gid = w * GPW + lane;
    const float4 pa = wsA[gid];                // stays in 4 VGPRs for the sweep

    // per-lane RAY coords (lane = ray within this block) -- every wave loads
    // the same 64 rays so readlane/bpermute can broadcast them.
    const int b  = blockIdx.x * RPB + lane;
    const int bb = (b < B) ? b : (B - 1);
    float2 p2 = *(const float2*)(x + 2 * bb);
    const float pnx = p2.x * (1.0f / 256.0f) - 1.0f;
    const float pny = p2.y * (1.0f / 256.0f) - 1.0f;
    const int ipnx = __builtin_bit_cast(int, pnx);
    const int ipny = __builtin_bit_cast(int, pny);

    #pragma unroll
    for (int c = 0; c < 3; ++c) acc[w][lane * 3 + c] = 0.0f;
    __syncthreads();                            // acc slices zeroed

    int qlen = 0;

    // dense drain; trip count is wave-uniform so every ds_bpermute executes
    // with all 64 lanes active (bpermute from a disabled lane is undefined).
    auto flush = [&]() {
        const int qtot = (qlen + 63) & ~63;
        for (int qi = lane; qi < qtot; qi += 64) {
            const bool live = (qi < qlen);
            const int e  = live ? (int)queue[w][qi] : 0;  // entry 0: valid idxs
            const int r  = e >> 6;              // ray lane
            const int gl = e & 63;              // gaussian lane
            const float qx = __builtin_bit_cast(float,
                __builtin_amdgcn_ds_bpermute(r << 2, ipnx));
            const float qy = __builtin_bit_cast(float,
                __builtin_amdgcn_ds_bpermute(r << 2, ipny));
            const int g = w * GPW + gl;
            const float4 pb = wsA[g];           // per-lane vector load, L1-hit
            const float sx = fmaf(qx, pb.x, pb.z);
            const float sy = fmaf(qy, pb.y, pb.w);
            const float4* hp = (const float4*)(wsH + ((size_t)g << 5));
            const float4 f0 = hp[0], f1 = hp[1], f2 = hp[2], f3 = hp[3];
            const float4 f4 = hp[4], f5 = hp[5], f6 = hp[6], f7 = hp[7];
            const float c = f0.x, s = f0.y, w0 = f0.z, iSx = f0.w, iSy = f1.x;
            float rx = fmaf(c, sx, -s * sy);
            float ry = fmaf(s, sx,  c * sy);
            float d2 = fmaf(rx, rx, ry * ry);
            float vx  = sx * iSx;
            float vy  = sy * iSy;
            float len = sqrtf(fmaf(vx, vx, vy * vy));
            float inv = __builtin_amdgcn_rcpf(1e-10f + len);
            float rvx = fmaf(c, vx, -s * vy);
            float rvy = fmaf(s, vx,  c * vy);
            float s1 = rvx * inv, c1 = rvy * inv;
            float s2 = 2.0f * s1 * c1;
            float c2 = fmaf(c1, c1, -s1 * s1);
            float s3 = fmaf(s2, c1,  c2 * s1);
            float c3 = fmaf(c2, c1, -s2 * s1);
            float s4 = 2.0f * s2 * c2;
            float c4 = fmaf(c2, c2, -s2 * s2);
            float rr = f1.y, gg = f1.z, bb2 = f1.w;          // sh0..2
            rr = fmaf(s1, f2.x, rr);  gg = fmaf(s1, f2.y, gg);  bb2 = fmaf(s1, f2.z, bb2);
            rr = fmaf(c1, f2.w, rr);  gg = fmaf(c1, f3.x, gg);  bb2 = fmaf(c1, f3.y, bb2);
            rr = fmaf(s2, f3.z, rr);  gg = fmaf(s2, f3.w, gg);  bb2 = fmaf(s2, f4.x, bb2);
            rr = fmaf(c2, f4.y, rr);  gg = fmaf(c2, f4.z, gg);  bb2 = fmaf(c2, f4.w, bb2);
            rr = fmaf(s3, f5.x, rr);  gg = fmaf(s3, f5.y, gg);  bb2 = fmaf(s3, f5.z, bb2);
            rr = fmaf(c3, f5.w, rr);  gg = fmaf(c3, f6.x, gg);  bb2 = fmaf(c3, f6.y, bb2);
            rr = fmaf(s4, f6.z, rr);  gg = fmaf(s4, f6.w, gg);  bb2 = fmaf(s4, f7.x, bb2);
            rr = fmaf(c4, f7.y, rr);  gg = fmaf(c4, f7.z, gg);  bb2 = fmaf(c4, f7.w, bb2);
            rr  = __builtin_amdgcn_rcpf(1.0f + __expf(-rr));
            gg  = __builtin_amdgcn_rcpf(1.0f + __expf(-gg));
            bb2 = __builtin_amdgcn_rcpf(1.0f + __expf(-bb2));
            float wt = __expf(-d2) * w0;
            if (live) {
                atomicAdd(&acc[w][r * 3 + 0], wt * rr);      // ds_add_f32
                atomicAdd(&acc[w][r * 3 + 1], wt * gg);
                atomicAdd(&acc[w][r * 3 + 2], wt * bb2);
            }
        }
        qlen = 0;
    };

    // ---- cheap sweep: 64 rays x this wave's 64 gaussians, zero memory ops ----
    #pragma unroll
    for (int r = 0; r < RPB; ++r) {
        const float spx = __builtin_bit_cast(float,
            __builtin_amdgcn_readlane(ipnx, r));             // uniform (SGPR)
        const float spy = __builtin_bit_cast(float,
            __builtin_amdgcn_readlane(ipny, r));
        float sx = fmaf(spx, pa.x, pa.z);       // 1 SGPR operand per fma
        float sy = fmaf(spy, pa.y, pa.w);
        float t  = fmaf(sx, sx, sy * sy);       // == dist^2 (R is rotation)
        bool  v  = t < 25.0f;
        unsigned long long mask = __ballot(v);
        if (mask) {
            int prefix = __popcll(mask & ((1ull << lane) - 1ull));
            if (v) queue[w][qlen + prefix] = (unsigned short)((r << 6) | lane);
            qlen += __popcll(mask);
            if (qlen > QCAP - 64) flush();      // cannot overflow next iter
        }
    }
    flush();

    // ---- reduce partials across the 8 waves ----
    __syncthreads();
    if (tid < RPB * 3) {
        float s = 0.0f;
        #pragma unroll
        for (int w2 = 0; w2 < NW; ++w2)
            s += acc[w2][tid];                  // consecutive: conflict-free
        const int idx = blockIdx.x * (RPB * 3) + tid;
        if (idx < 3 * B)
            out[idx] = s;
    }
}

extern "C" void kernel_launch(void* const* d_in, const int* in_sizes, int n_in,
                              void* d_out, int out_size, void* d_ws, size_t ws_size,
                              hipStream_t stream) {
    const float* x       = (const float*)d_in[0];
    const float* rgbsh   = (const float*)d_in[1];
    const float* opacity = (const float*)d_in[2];
    const float* mu      = (const float*)d_in[3];
    const float* scale   = (const float*)d_in[4];
    const float* angle   = (const float*)d_in[5];
    float* out = (float*)d_out;

    const int B = in_sizes[0] / 2;   // 32768
    const int N = in_sizes[2];       // 512

    // workspace: [wsA: N float4 (8 KB)][wsH: N*32 floats (64 KB)]
    char* ws = (char*)d_ws;
    float4* wsA = (float4*)(ws);
    float*  wsH = (float*)(ws + (size_t)N * 16);

    pre_kernel<<<(N + 255) / 256, 256, 0, stream>>>(rgbsh, opacity, mu, scale,
                                                    angle, wsA, wsH, N);
    splat_kernel<<<(B + RPB - 1) / RPB, BDIM, 0, stream>>>(x, wsA, wsH, out, B);
}

// Round 9
// 69.775 us; speedup vs baseline: 1.1077x; 1.0333x over previous
//
#include <hip/hip_runtime.h>

#define BDIM 512       // 8 waves; wave w owns gaussians [64w, 64w+64)
#define NW   8
#define RPB  64        // rays per block
#define GPW  64        // gaussians per wave (== wavefront size)
#define QCAP 256       // per-wave hit-queue capacity (flush at QCAP-64)
#define PROW 12        // floats per LDS param row (48 B, 16B-aligned)

// ---------------------------------------------------------------------------
// Single dispatch, zero workspace. lane = GAUSSIAN: each lane derives its own
// gaussian's params in-register at startup (tanh/sincos/exp once per lane,
// fully parallel) -- no pre_kernel, no ws round-trip. The 16.7M-pair cheap
// sweep is pure VALU (affine params live in 4 VGPRs; ray coords broadcast by
// v_readlane, loop fully unrolled). Hits are ballot-compacted into a
// per-wave LDS queue and drained densely: ray coords via ds_bpermute
// (uniform trip count -- all 64 lanes active, dead lanes clamped to entry 0
// and predicated off the accumulate; bpermute from an EXEC-disabled lane is
// undefined), gaussian params gathered from a per-wave LDS table
// (ds_read_b128 x3), SH coeffs straight from L2-resident rgbsh. ds_add_f32
// into per-wave acc slices; one coalesced store per ray.
// LDS = 34.8 KB; grid 512 -> 2 blocks/CU = 16 waves/CU.
// ---------------------------------------------------------------------------

__global__ __launch_bounds__(BDIM, 4) void splat_kernel(
    const float* __restrict__ x,        // (B,2)
    const float* __restrict__ rgbsh,    // (N,9,3)
    const float* __restrict__ opacity,  // (N)
    const float* __restrict__ mu,       // (N,2)
    const float* __restrict__ scale,    // (N,2)
    const float* __restrict__ angle,    // (N)
    float* __restrict__ out,            // (B,3)
    int B, int N)
{
    __shared__ float prm[NW][GPW][PROW];       // 24 KB param table
    __shared__ float acc[NW][RPB * 3];         //  6 KB per-wave acc slices
    __shared__ unsigned short queue[NW][QCAP]; //  4 KB hit queues

    const int tid  = threadIdx.x;
    const int lane = tid & 63;
    const int w    = __builtin_amdgcn_readfirstlane(tid >> 6);
    const int gid  = w * GPW + lane;           // this lane's gaussian

    // ---- per-lane ray coords (lane = ray within this block) ----
    const int b  = blockIdx.x * RPB + lane;
    const int bb = (b < B) ? b : (B - 1);
    float2 p2 = *(const float2*)(x + 2 * bb);
    const float pnx = p2.x * (1.0f / 256.0f) - 1.0f;
    const float pny = p2.y * (1.0f / 256.0f) - 1.0f;
    const int ipnx = __builtin_bit_cast(int, pnx);
    const int ipny = __builtin_bit_cast(int, pny);

    // ---- per-lane gaussian derived params (in-register; once) ----
    float pax, pay, pbx, pby;                  // sweep affine, stays in VGPRs
    {
        const float S_MIN = 1.0f / 30.0f;
        const float S_MAX = 1.0f / 0.75f;
        float2 muv = *(const float2*)(mu + 2 * gid);
        float2 scv = *(const float2*)(scale + 2 * gid);
        float gmx = tanhf(muv.x) * 1.05f;
        float gmy = tanhf(muv.y) * 1.05f;
        float Sx = fminf(fmaxf(scv.x, 0.0f), 1.0f) * (S_MAX - S_MIN) + S_MIN;
        float Sy = fminf(fmaxf(scv.y, 0.0f), 1.0f) * (S_MAX - S_MIN) + S_MIN;
        pax = 256.0f * Sx;  pay = 256.0f * Sy;
        pbx = -gmx * pax;   pby = -gmy * pay;
        float a = tanhf(angle[gid]) * 3.1416f;
        float sa, ca;
        sincosf(a, &sa, &ca);
        float w0 = 1.0f / (1.0f + expf(-opacity[gid]));
        float* pr = &prm[w][lane][0];          // wave-private: no block sync
        pr[0] = pax; pr[1] = pay; pr[2] = pbx; pr[3] = pby;
        pr[4] = ca;  pr[5] = sa;  pr[6] = w0;
        pr[7] = 1.0f / Sx;  pr[8] = 1.0f / Sy;
    }
    #pragma unroll
    for (int c = 0; c < 3; ++c) acc[w][lane * 3 + c] = 0.0f;

    int qlen = 0;

    // dense drain; trip count is wave-uniform so every ds_bpermute executes
    // with all 64 lanes active. Dead lanes use entry 0 (valid indices).
    auto flush = [&]() {
        const int qtot = (qlen + 63) & ~63;
        for (int qi = lane; qi < qtot; qi += 64) {
            const bool live = (qi < qlen);
            const int e  = live ? (int)queue[w][qi] : 0;
            const int r  = e >> 6;              // ray lane
            const int gl = e & 63;              // gaussian lane
            const float qx = __builtin_bit_cast(float,
                __builtin_amdgcn_ds_bpermute(r << 2, ipnx));
            const float qy = __builtin_bit_cast(float,
                __builtin_amdgcn_ds_bpermute(r << 2, ipny));
            const float4 g0 = *(const float4*)&prm[w][gl][0];  // ax,ay,bx,by
            const float4 g1 = *(const float4*)&prm[w][gl][4];  // c,s,w0,iSx
            const float iSy = prm[w][gl][8];
            const float sx = fmaf(qx, g0.x, g0.z);
            const float sy = fmaf(qy, g0.y, g0.w);
            const float c = g1.x, s = g1.y, w0 = g1.z, iSx = g1.w;
            float rx = fmaf(c, sx, -s * sy);
            float ry = fmaf(s, sx,  c * sy);
            float d2 = fmaf(rx, rx, ry * ry);
            float vx  = sx * iSx;
            float vy  = sy * iSy;
            float len = sqrtf(fmaf(vx, vx, vy * vy));
            float inv = __builtin_amdgcn_rcpf(1e-10f + len);
            float rvx = fmaf(c, vx, -s * vy);
            float rvy = fmaf(s, vx,  c * vy);
            float s1 = rvx * inv, c1 = rvy * inv;
            float s2 = 2.0f * s1 * c1;
            float c2 = fmaf(c1, c1, -s1 * s1);
            float s3 = fmaf(s2, c1,  c2 * s1);
            float c3 = fmaf(c2, c1, -s2 * s1);
            float s4 = 2.0f * s2 * c2;
            float c4 = fmaf(c2, c2, -s2 * s2);
            // SH coeffs straight from L2-resident rgbsh (rare path)
            const float* sh = rgbsh + (size_t)(w * GPW + gl) * 27;
            float rr = sh[0], gg = sh[1], bb2 = sh[2];
            rr = fmaf(s1, sh[ 3], rr);  gg = fmaf(s1, sh[ 4], gg);  bb2 = fmaf(s1, sh[ 5], bb2);
            rr = fmaf(c1, sh[ 6], rr);  gg = fmaf(c1, sh[ 7], gg);  bb2 = fmaf(c1, sh[ 8], bb2);
            rr = fmaf(s2, sh[ 9], rr);  gg = fmaf(s2, sh[10], gg);  bb2 = fmaf(s2, sh[11], bb2);
            rr = fmaf(c2, sh[12], rr);  gg = fmaf(c2, sh[13], gg);  bb2 = fmaf(c2, sh[14], bb2);
            rr = fmaf(s3, sh[15], rr);  gg = fmaf(s3, sh[16], gg);  bb2 = fmaf(s3, sh[17], bb2);
            rr = fmaf(c3, sh[18], rr);  gg = fmaf(c3, sh[19], gg);  bb2 = fmaf(c3, sh[20], bb2);
            rr = fmaf(s4, sh[21], rr);  gg = fmaf(s4, sh[22], gg);  bb2 = fmaf(s4, sh[23], bb2);
            rr = fmaf(c4, sh[24], rr);  gg = fmaf(c4, sh[25], gg);  bb2 = fmaf(c4, sh[26], bb2);
            rr  = __builtin_amdgcn_rcpf(1.0f + __expf(-rr));
            gg  = __builtin_amdgcn_rcpf(1.0f + __expf(-gg));
            bb2 = __builtin_amdgcn_rcpf(1.0f + __expf(-bb2));
            float wt = __expf(-d2) * w0;
            if (live) {
                atomicAdd(&acc[w][r * 3 + 0], wt * rr);      // ds_add_f32
                atomicAdd(&acc[w][r * 3 + 1], wt * gg);
                atomicAdd(&acc[w][r * 3 + 2], wt * bb2);
            }
        }
        qlen = 0;
    };

    // ---- cheap sweep: 64 rays x this wave's 64 gaussians, zero memory ops ----
    #pragma unroll
    for (int r = 0; r < RPB; ++r) {
        const float spx = __builtin_bit_cast(float,
            __builtin_amdgcn_readlane(ipnx, r));             // uniform (SGPR)
        const float spy = __builtin_bit_cast(float,
            __builtin_amdgcn_readlane(ipny, r));
        float sx = fmaf(spx, pax, pbx);         // 1 SGPR operand per fma
        float sy = fmaf(spy, pay, pby);
        float t  = fmaf(sx, sx, sy * sy);       // == dist^2 (R is rotation)
        bool  v  = t < 25.0f;
        unsigned long long mask = __ballot(v);
        if (mask) {
            int prefix = __popcll(mask & ((1ull << lane) - 1ull));
            if (v) queue[w][qlen + prefix] = (unsigned short)((r << 6) | lane);
            qlen += __popcll(mask);
            if (qlen > QCAP - 64) flush();      // cannot overflow next iter
        }
    }
    flush();

    // ---- reduce partials across the 8 waves ----
    __syncthreads();
    if (tid < RPB * 3) {
        float s = 0.0f;
        #pragma unroll
        for (int w2 = 0; w2 < NW; ++w2)
            s += acc[w2][tid];                  // consecutive: conflict-free
        const int idx = blockIdx.x * (RPB * 3) + tid;
        if (idx < 3 * B)
            out[idx] = s;
    }
}

extern "C" void kernel_launch(void* const* d_in, const int* in_sizes, int n_in,
                              void* d_out, int out_size, void* d_ws, size_t ws_size,
                              hipStream_t stream) {
    const float* x       = (const float*)d_in[0];
    const float* rgbsh   = (const float*)d_in[1];
    const float* opacity = (const float*)d_in[2];
    const float* mu      = (const float*)d_in[3];
    const float* scale   = (const float*)d_in[4];
    const float* angle   = (const float*)d_in[5];
    float* out = (float*)d_out;

    const int B = in_sizes[0] / 2;   // 32768
    const int N = in_sizes[2];       // 512

    splat_kernel<<<(B + RPB - 1) / RPB, BDIM, 0, stream>>>(
        x, rgbsh, opacity, mu, scale, angle, out, B, N);
}

// Round 10
// 68.737 us; speedup vs baseline: 1.1245x; 1.0151x over previous
//
#include <hip/hip_runtime.h>

#define BDIM 512       // 8 waves; wave w owns gaussians [64w, 64w+64)
#define NW   8
#define RPB  64        // rays per block
#define GPW  64        // gaussians per wave (== wavefront size)
#define QCAP 256       // per-wave hit-queue capacity (flush at QCAP-64)
#define PROW 12        // floats per LDS param row (48 B, 16B-aligned)

// ---------------------------------------------------------------------------
// Single dispatch, zero workspace (R9 structure) + fast-native startup math.
// lane = GAUSSIAN: each lane derives its own gaussian's params in-register
// using hardware transcendentals (v_exp/v_sin/v_cos/v_rcp) instead of libm
// tanhf/sincosf/expf + full-precision divides -- inputs are bounded
// (|mu|,|angle|<=1, opacity in [0,1], S in [1/30,4/3]) so the ~1e-6 native
// error is far under the 0.019 absmax threshold. Sweep: pure VALU, affine
// params in 4 VGPRs, ray coords broadcast by v_readlane (fully unrolled).
// Hits ballot-compacted into per-wave LDS queues, drained densely with a
// wave-uniform trip count (all 64 lanes active through ds_bpermute; dead
// lanes clamped to entry 0 and predicated off the ds_add_f32 accumulate).
// LDS = 34.8 KB; grid 512 -> 2 blocks/CU = 16 waves/CU.
// ---------------------------------------------------------------------------

__device__ __forceinline__ float ftanh(float v) {
    // tanh(v) = (e^{2v}-1)/(e^{2v}+1); |v|<=1.05 here -> no overflow path
    float e = __expf(2.0f * v);
    return (e - 1.0f) * __builtin_amdgcn_rcpf(e + 1.0f);
}

__global__ __launch_bounds__(BDIM, 4) void splat_kernel(
    const float* __restrict__ x,        // (B,2)
    const float* __restrict__ rgbsh,    // (N,9,3)
    const float* __restrict__ opacity,  // (N)
    const float* __restrict__ mu,       // (N,2)
    const float* __restrict__ scale,    // (N,2)
    const float* __restrict__ angle,    // (N)
    float* __restrict__ out,            // (B,3)
    int B, int N)
{
    __shared__ float prm[NW][GPW][PROW];       // 24 KB param table
    __shared__ float acc[NW][RPB * 3];         //  6 KB per-wave acc slices
    __shared__ unsigned short queue[NW][QCAP]; //  4 KB hit queues

    const int tid  = threadIdx.x;
    const int lane = tid & 63;
    const int w    = __builtin_amdgcn_readfirstlane(tid >> 6);
    const int gid  = w * GPW + lane;           // this lane's gaussian

    // ---- per-lane ray coords (lane = ray within this block) ----
    const int b  = blockIdx.x * RPB + lane;
    const int bb = (b < B) ? b : (B - 1);
    float2 p2 = *(const float2*)(x + 2 * bb);
    const float pnx = p2.x * (1.0f / 256.0f) - 1.0f;
    const float pny = p2.y * (1.0f / 256.0f) - 1.0f;
    const int ipnx = __builtin_bit_cast(int, pnx);
    const int ipny = __builtin_bit_cast(int, pny);

    // ---- per-lane gaussian derived params (in-register; native math) ----
    float pax, pay, pbx, pby;                  // sweep affine, stays in VGPRs
    {
        const float S_MIN = 1.0f / 30.0f;
        const float S_MAX = 1.0f / 0.75f;
        float2 muv = *(const float2*)(mu + 2 * gid);
        float2 scv = *(const float2*)(scale + 2 * gid);
        float gmx = ftanh(muv.x) * 1.05f;
        float gmy = ftanh(muv.y) * 1.05f;
        float Sx = fminf(fmaxf(scv.x, 0.0f), 1.0f) * (S_MAX - S_MIN) + S_MIN;
        float Sy = fminf(fmaxf(scv.y, 0.0f), 1.0f) * (S_MAX - S_MIN) + S_MIN;
        pax = 256.0f * Sx;  pay = 256.0f * Sy;
        pbx = -gmx * pax;   pby = -gmy * pay;
        float a  = ftanh(angle[gid]) * 3.1416f;
        float sa = __sinf(a), ca = __cosf(a);  // native v_sin/v_cos
        float w0 = __builtin_amdgcn_rcpf(1.0f + __expf(-opacity[gid]));
        *(float4*)&prm[w][lane][0] = make_float4(pax, pay, pbx, pby);
        *(float4*)&prm[w][lane][4] = make_float4(ca, sa, w0,
                                                 __builtin_amdgcn_rcpf(Sx));
        prm[w][lane][8] = __builtin_amdgcn_rcpf(Sy);
    }
    #pragma unroll
    for (int c = 0; c < 3; ++c) acc[w][lane * 3 + c] = 0.0f;

    int qlen = 0;

    // dense drain; trip count is wave-uniform so every ds_bpermute executes
    // with all 64 lanes active. Dead lanes use entry 0 (valid indices).
    auto flush = [&]() {
        const int qtot = (qlen + 63) & ~63;
        for (int qi = lane; qi < qtot; qi += 64) {
            const bool live = (qi < qlen);
            const int e  = live ? (int)queue[w][qi] : 0;
            const int r  = e >> 6;              // ray lane
            const int gl = e & 63;              // gaussian lane
            const float qx = __builtin_bit_cast(float,
                __builtin_amdgcn_ds_bpermute(r << 2, ipnx));
            const float qy = __builtin_bit_cast(float,
                __builtin_amdgcn_ds_bpermute(r << 2, ipny));
            const float4 g0 = *(const float4*)&prm[w][gl][0];  // ax,ay,bx,by
            const float4 g1 = *(const float4*)&prm[w][gl][4];  // c,s,w0,iSx
            const float iSy = prm[w][gl][8];
            const float sx = fmaf(qx, g0.x, g0.z);
            const float sy = fmaf(qy, g0.y, g0.w);
            const float c = g1.x, s = g1.y, w0 = g1.z, iSx = g1.w;
            float rx = fmaf(c, sx, -s * sy);
            float ry = fmaf(s, sx,  c * sy);
            float d2 = fmaf(rx, rx, ry * ry);
            float vx  = sx * iSx;
            float vy  = sy * iSy;
            float len = sqrtf(fmaf(vx, vx, vy * vy));
            float inv = __builtin_amdgcn_rcpf(1e-10f + len);
            float rvx = fmaf(c, vx, -s * vy);
            float rvy = fmaf(s, vx,  c * vy);
            float s1 = rvx * inv, c1 = rvy * inv;
            float s2 = 2.0f * s1 * c1;
            float c2 = fmaf(c1, c1, -s1 * s1);
            float s3 = fmaf(s2, c1,  c2 * s1);
            float c3 = fmaf(c2, c1, -s2 * s1);
            float s4 = 2.0f * s2 * c2;
            float c4 = fmaf(c2, c2, -s2 * s2);
            // SH coeffs straight from L2-resident rgbsh (rare path)
            const float* sh = rgbsh + (size_t)(w * GPW + gl) * 27;
            float rr = sh[0], gg = sh[1], bb2 = sh[2];
            rr = fmaf(s1, sh[ 3], rr);  gg = fmaf(s1, sh[ 4], gg);  bb2 = fmaf(s1, sh[ 5], bb2);
            rr = fmaf(c1, sh[ 6], rr);  gg = fmaf(c1, sh[ 7], gg);  bb2 = fmaf(c1, sh[ 8], bb2);
            rr = fmaf(s2, sh[ 9], rr);  gg = fmaf(s2, sh[10], gg);  bb2 = fmaf(s2, sh[11], bb2);
            rr = fmaf(c2, sh[12], rr);  gg = fmaf(c2, sh[13], gg);  bb2 = fmaf(c2, sh[14], bb2);
            rr = fmaf(s3, sh[15], rr);  gg = fmaf(s3, sh[16], gg);  bb2 = fmaf(s3, sh[17], bb2);
            rr = fmaf(c3, sh[18], rr);  gg = fmaf(c3, sh[19], gg);  bb2 = fmaf(c3, sh[20], bb2);
            rr = fmaf(s4, sh[21], rr);  gg = fmaf(s4, sh[22], gg);  bb2 = fmaf(s4, sh[23], bb2);
            rr = fmaf(c4, sh[24], rr);  gg = fmaf(c4, sh[25], gg);  bb2 = fmaf(c4, sh[26], bb2);
            rr  = __builtin_amdgcn_rcpf(1.0f + __expf(-rr));
            gg  = __builtin_amdgcn_rcpf(1.0f + __expf(-gg));
            bb2 = __builtin_amdgcn_rcpf(1.0f + __expf(-bb2));
            float wt = __expf(-d2) * w0;
            if (live) {
                atomicAdd(&acc[w][r * 3 + 0], wt * rr);      // ds_add_f32
                atomicAdd(&acc[w][r * 3 + 1], wt * gg);
                atomicAdd(&acc[w][r * 3 + 2], wt * bb2);
            }
        }
        qlen = 0;
    };

    // ---- cheap sweep: 64 rays x this wave's 64 gaussians, zero memory ops ----
    #pragma unroll
    for (int r = 0; r < RPB; ++r) {
        const float spx = __builtin_bit_cast(float,
            __builtin_amdgcn_readlane(ipnx, r));             // uniform (SGPR)
        const float spy = __builtin_bit_cast(float,
            __builtin_amdgcn_readlane(ipny, r));
        float sx = fmaf(spx, pax, pbx);         // 1 SGPR operand per fma
        float sy = fmaf(spy, pay, pby);
        float t  = fmaf(sx, sx, sy * sy);       // == dist^2 (R is rotation)
        bool  v  = t < 25.0f;
        unsigned long long mask = __ballot(v);
        if (mask) {
            int prefix = __popcll(mask & ((1ull << lane) - 1ull));
            if (v) queue[w][qlen + prefix] = (unsigned short)((r << 6) | lane);
            qlen += __popcll(mask);
            if (qlen > QCAP - 64) flush();      // cannot overflow next iter
        }
    }
    flush();

    // ---- reduce partials across the 8 waves ----
    __syncthreads();
    if (tid < RPB * 3) {
        float s = 0.0f;
        #pragma unroll
        for (int w2 = 0; w2 < NW; ++w2)
            s += acc[w2][tid];                  // consecutive: conflict-free
        const int idx = blockIdx.x * (RPB * 3) + tid;
        if (idx < 3 * B)
            out[idx] = s;
    }
}

extern "C" void kernel_launch(void* const* d_in, const int* in_sizes, int n_in,
                              void* d_out, int out_size, void* d_ws, size_t ws_size,
                              hipStream_t stream) {
    const float* x       = (const float*)d_in[0];
    const float* rgbsh   = (const float*)d_in[1];
    const float* opacity = (const float*)d_in[2];
    const float* mu      = (const float*)d_in[3];
    const float* scale   = (const float*)d_in[4];
    const float* angle   = (const float*)d_in[5];
    float* out = (float*)d_out;

    const int B = in_sizes[0] / 2;   // 32768
    const int N = in_sizes[2];       // 512

    splat_kernel<<<(B + RPB - 1) / RPB, BDIM, 0, stream>>>(
        x, rgbsh, opacity, mu, scale, angle, out, B, N);
}